// Round 2
// baseline (173.980 us; speedup 1.0000x reference)
//
#include <hip/hip_runtime.h>
#include <math.h>

constexpr int NH     = 7;
constexpr int NDIST  = 4;
constexpr int NTHETA = 8;
constexpr int EDIM   = 16;
constexpr int NPB    = 8;    // points per block
constexpr int BLOCK  = 256;

__global__ __launch_bounds__(BLOCK) void grid_layer_kernel(
    const float* __restrict__ x,        // (N, 16)
    const float* __restrict__ coords,   // (2, N): [0]=lon, [1]=lat
    const float* __restrict__ sigma_p,  // (1)
    const float* __restrict__ kappa_p,  // (1)
    const int*   __restrict__ lidx,     // (N)
    const int*   __restrict__ adjc,     // (N, 7)
    float*       __restrict__ out,      // (N, 4, 8, 16)
    int N)
{
    __shared__ float2 geom[NPB][NH];          // (dist, phi) -- phi stored directly
    __shared__ float4 xs[NPB][NH][EDIM / 4];  // staged neighbor features

    const int tid = threadIdx.x;
    const int n0  = blockIdx.x * NPB;

    const float sigma   = sigma_p[0];
    const float kappa   = kappa_p[0];
    const float inv_s   = 1.0f / sigma;

    // ---- Phase 1a: stage x neighbors (224 threads, one float4 each) ----
    if (tid < NPB * NH * 4) {
        const int p  = tid >> 2;
        const int q  = tid & 3;
        const int nl = p / NH;
        const int k  = p - nl * NH;
        const int n  = n0 + nl;
        if (n < N) {
            const int idx = adjc[(size_t)lidx[n] * NH + k];
            xs[nl][k][q] = ((const float4*)(x + (size_t)idx * EDIM))[q];
        }
    }

    // ---- Phase 1b: geometry per (n, k) (56 threads) — exact reference mirror ----
    if (tid < NPB * NH) {
        const int nl = tid / NH;
        const int k  = tid - nl * NH;
        const int n  = n0 + nl;
        if (n < N) {
            const int li   = lidx[n];
            const int idx0 = adjc[(size_t)li * NH];      // "center" = neighbor 0
            const int idxk = adjc[(size_t)li * NH + k];
            const float lon1 = coords[idx0], lat1 = coords[N + idx0];
            const float lon2 = coords[idxk], lat2 = coords[N + idxk];
            const float dlon = lon2 - lon1;
            const float sl1 = sinf(lat1), cl1 = cosf(lat1);
            const float sl2 = sinf(lat2), cl2 = cosf(lat2);
            const float sdl = sinf(dlon), cdl = cosf(dlon);
            float cos_d = sl1 * sl2 + cl1 * cl2 * cdl;
            cos_d = fminf(fmaxf(cos_d, -1.0f + 1e-7f), 1.0f - 1e-7f);
            const float dist = acosf(cos_d);
            const float phi  = atan2f(sdl * cl2, cl1 * sl2 - sl1 * cl2 * cdl);
            geom[nl][k] = make_float2(dist, phi);
        }
    }
    __syncthreads();

    // ---- Phase 2: thread = (n_local, theta, e4) ----
    const int nl = tid >> 5;     // 0..7
    const int j  = tid & 31;
    const int t  = j >> 2;       // 0..7
    const int e4 = j & 3;        // 0..3
    const int n  = n0 + nl;
    if (n >= N) return;

    const float theta = -3.14159265358979f + (float)t * 0.78539816339745f;

    // w[d][t][k] = exp(kappa*cos(theta - phi_k)) * exp(-0.5*((dp_d - dist_k)/sigma)^2)
    // computed as one expf of the summed exponent (identical up to 1 ulp).
    float w[NDIST][NH];
    #pragma unroll
    for (int k = 0; k < NH; ++k) {
        const float2 g   = geom[nl][k];
        const float  ang = kappa * cosf(theta - g.y);
        #pragma unroll
        for (int d = 0; d < NDIST; ++d) {
            const float dp = 0.066666667f * (float)d;  // linspace(0, 0.2, 4)
            const float z  = (dp - g.x) * inv_s;
            w[d][k] = expf(ang - 0.5f * z * z);
        }
    }
    #pragma unroll
    for (int d = 0; d < NDIST; ++d) {
        float s = 0.0f;
        #pragma unroll
        for (int k = 0; k < NH; ++k) s += w[d][k];
        const float inv = 1.0f / (s + 1e-10f);
        #pragma unroll
        for (int k = 0; k < NH; ++k) w[d][k] *= inv;
    }

    float4 acc[NDIST];
    #pragma unroll
    for (int d = 0; d < NDIST; ++d) acc[d] = make_float4(0.f, 0.f, 0.f, 0.f);
    #pragma unroll
    for (int k = 0; k < NH; ++k) {
        const float4 xv = xs[nl][k][e4];
        #pragma unroll
        for (int d = 0; d < NDIST; ++d) {
            acc[d].x += w[d][k] * xv.x;
            acc[d].y += w[d][k] * xv.y;
            acc[d].z += w[d][k] * xv.z;
            acc[d].w += w[d][k] * xv.w;
        }
    }

    // out[n, d, t, e]: lanes j=0..31 of each n write consecutive float4s per d
    float4* outp = (float4*)(out + (size_t)n * (NDIST * NTHETA * EDIM));
    #pragma unroll
    for (int d = 0; d < NDIST; ++d) {
        outp[d * (NTHETA * EDIM / 4) + t * (EDIM / 4) + e4] = acc[d];
    }
}

extern "C" void kernel_launch(void* const* d_in, const int* in_sizes, int n_in,
                              void* d_out, int out_size, void* d_ws, size_t ws_size,
                              hipStream_t stream) {
    const float* x      = (const float*)d_in[0];
    const float* coords = (const float*)d_in[1];
    const float* sigma  = (const float*)d_in[2];
    const float* kappa  = (const float*)d_in[3];
    const int*   lidx   = (const int*)d_in[4];
    const int*   adjc   = (const int*)d_in[5];
    float*       out    = (float*)d_out;

    const int N = in_sizes[4];  // local_indices has N elements (B=1)
    const int grid = (N + NPB - 1) / NPB;
    hipLaunchKernelGGL(grid_layer_kernel, dim3(grid), dim3(BLOCK), 0, stream,
                       x, coords, sigma, kappa, lidx, adjc, out, N);
}

// Round 3
// 162.833 us; speedup vs baseline: 1.0685x; 1.0685x over previous
//
#include <hip/hip_runtime.h>
#include <math.h>

constexpr int NH     = 7;
constexpr int NDIST  = 4;
constexpr int NTHETA = 8;
constexpr int EDIM   = 16;
constexpr int NPB    = 8;    // points per block
constexpr int BLOCK  = 256;

__global__ __launch_bounds__(BLOCK) void grid_layer_kernel(
    const float* __restrict__ x,        // (N, 16)
    const float* __restrict__ coords,   // (2, N): [0]=lon, [1]=lat
    const float* __restrict__ sigma_p,  // (1)
    const float* __restrict__ kappa_p,  // (1)
    const int*   __restrict__ lidx,     // (N)
    const int*   __restrict__ adjc,     // (N, 7)
    float*       __restrict__ out,      // (N, 4, 8, 16)
    int N)
{
    __shared__ float2 geom[NPB][NH];            // (dist, phi)
    __shared__ float4 xs[NPB][NH][EDIM / 4];    // staged neighbor features
    __shared__ float  vm_s[NPB][NTHETA][NH];    // exp(kappa*cos(theta_t - phi_k))
    __shared__ float  nd_s[NPB][NDIST][NH];     // exp(-0.5*((dp_d - dist_k)/s)^2)

    const int tid = threadIdx.x;
    const int n0  = blockIdx.x * NPB;

    const float sigma = sigma_p[0];
    const float kappa = kappa_p[0];
    const float inv_s = 1.0f / sigma;

    // ---- Phase 1a: stage x neighbors (224 threads, one float4 each) ----
    if (tid < NPB * NH * 4) {
        const int p  = tid >> 2;
        const int q  = tid & 3;
        const int nl = p / NH;
        const int k  = p - nl * NH;
        const int n  = n0 + nl;
        if (n < N) {
            const int idx = adjc[(size_t)lidx[n] * NH + k];
            xs[nl][k][q] = ((const float4*)(x + (size_t)idx * EDIM))[q];
        }
    }

    // ---- Phase 1b: geometry + distance factor per (n,k) (56 threads) ----
    if (tid < NPB * NH) {
        const int nl = tid / NH;
        const int k  = tid - nl * NH;
        const int n  = n0 + nl;
        if (n < N) {
            const int li   = lidx[n];
            const int idx0 = adjc[(size_t)li * NH];      // "center" = neighbor 0
            const int idxk = adjc[(size_t)li * NH + k];
            const float lon1 = coords[idx0], lat1 = coords[N + idx0];
            const float lon2 = coords[idxk], lat2 = coords[N + idxk];
            const float dlon = lon2 - lon1;
            const float sl1 = sinf(lat1), cl1 = cosf(lat1);
            const float sl2 = sinf(lat2), cl2 = cosf(lat2);
            const float sdl = sinf(dlon), cdl = cosf(dlon);
            float cos_d = sl1 * sl2 + cl1 * cl2 * cdl;
            cos_d = fminf(fmaxf(cos_d, -1.0f + 1e-7f), 1.0f - 1e-7f);
            const float dist = acosf(cos_d);
            const float phi  = atan2f(sdl * cl2, cl1 * sl2 - sl1 * cl2 * cdl);
            geom[nl][k] = make_float2(dist, phi);
            #pragma unroll
            for (int d = 0; d < NDIST; ++d) {
                const float dp = 0.066666667f * (float)d;  // linspace(0, 0.2, 4)
                const float z  = (dp - dist) * inv_s;
                nd_s[nl][d][k] = expf(-0.5f * z * z);
            }
        }
    }
    __syncthreads();

    // ---- Phase 1c: von-Mises factor per (n,k,theta-pair) (224 threads) ----
    if (tid < NPB * NH * 4) {
        const int nl  = tid / (NH * 4);
        const int r   = tid - nl * (NH * 4);
        const int k   = r >> 2;
        const int th2 = r & 3;
        const int n   = n0 + nl;
        if (n < N) {
            const float phi = geom[nl][k].y;
            #pragma unroll
            for (int i = 0; i < 2; ++i) {
                const int t = th2 * 2 + i;
                const float theta = -3.14159265358979f + (float)t * 0.78539816339745f;
                vm_s[nl][t][k] = expf(kappa * cosf(theta - phi));
            }
        }
    }
    __syncthreads();

    // ---- Phase 2: thread = (n_local, theta, e4) — pure mul/fma ----
    const int nl = tid >> 5;     // 0..7
    const int j  = tid & 31;
    const int t  = j >> 2;       // 0..7
    const int e4 = j & 3;        // 0..3
    const int n  = n0 + nl;
    if (n >= N) return;

    float  s[NDIST]   = {0.f, 0.f, 0.f, 0.f};
    float4 acc[NDIST];
    #pragma unroll
    for (int d = 0; d < NDIST; ++d) acc[d] = make_float4(0.f, 0.f, 0.f, 0.f);

    #pragma unroll
    for (int k = 0; k < NH; ++k) {
        const float  vmk = vm_s[nl][t][k];
        const float4 xv  = xs[nl][k][e4];
        #pragma unroll
        for (int d = 0; d < NDIST; ++d) {
            const float w = vmk * nd_s[nl][d][k];
            s[d] += w;
            acc[d].x += w * xv.x;
            acc[d].y += w * xv.y;
            acc[d].z += w * xv.z;
            acc[d].w += w * xv.w;
        }
    }

    // out[n, d, t, e]: lanes j=0..31 of each n write consecutive float4s per d
    float4* outp = (float4*)(out + (size_t)n * (NDIST * NTHETA * EDIM));
    #pragma unroll
    for (int d = 0; d < NDIST; ++d) {
        const float inv = 1.0f / (s[d] + 1e-10f);
        acc[d].x *= inv; acc[d].y *= inv; acc[d].z *= inv; acc[d].w *= inv;
        outp[d * (NTHETA * EDIM / 4) + t * (EDIM / 4) + e4] = acc[d];
    }
}

extern "C" void kernel_launch(void* const* d_in, const int* in_sizes, int n_in,
                              void* d_out, int out_size, void* d_ws, size_t ws_size,
                              hipStream_t stream) {
    const float* x      = (const float*)d_in[0];
    const float* coords = (const float*)d_in[1];
    const float* sigma  = (const float*)d_in[2];
    const float* kappa  = (const float*)d_in[3];
    const int*   lidx   = (const int*)d_in[4];
    const int*   adjc   = (const int*)d_in[5];
    float*       out    = (float*)d_out;

    const int N = in_sizes[4];  // local_indices has N elements (B=1)
    const int grid = (N + NPB - 1) / NPB;
    hipLaunchKernelGGL(grid_layer_kernel, dim3(grid), dim3(BLOCK), 0, stream,
                       x, coords, sigma, kappa, lidx, adjc, out, N);
}